// Round 6
// baseline (86.530 us; speedup 1.0000x reference)
//
#include <hip/hip_runtime.h>

// Conv2dfft == direct 3x3 cross-correlation, pad=1, + bias (FFT grid never wraps).
// x: [32,128,32,32] f32; w: [128,128,3,3] f32; b: [128] f32; out: [32,128,32,32] f32.
// R8: x-pack overlapped with the main loop. Phase group cc only reads x-chunk
// group cc, so: prologue packs cc0 only (1/4 of prior serial work); chunk cc+1
// is packed DURING phases 3cc..3cc+2 (8 scalar loads issued at phase start,
// cvt+ds_write_b128 after compute -> HBM latency hides under MFMA+ds_read).
// vmcnt FIFO invariant preserved: loads pinned before STAGE_W3 via sched_barrier;
// the ds_write's compiler wait (vmcnt(6)) subsumes the phase wait. lgkmcnt(0)
// fences ds_write visibility at writing phases' barriers. Main loop/epilogue
// otherwise identical to R7 (12 phases, triple-buffered weights, vmcnt(6)).

typedef __attribute__((ext_vector_type(8))) short bf16x8;
typedef __attribute__((ext_vector_type(4))) float f32x4;

#define N_IMG 32
#define C_IN  128
#define F_OUT 128
#define HW    32
#define HPAD  34

__device__ __forceinline__ unsigned short f2bf(float f) {
    union { float f; unsigned u; } v; v.f = f;
    unsigned r = v.u + 0x7fffu + ((v.u >> 16) & 1u);   // RNE
    return (unsigned short)(r >> 16);
}

// ------- pack w: [F,C,3,3] f32 -> [cc 4][tap 9][qk 4][f 128][c8 8] bf16 -------
__global__ __launch_bounds__(256) void pack_w_kernel(const float* __restrict__ w,
                                                     unsigned short* __restrict__ wpk) {
    int idx = blockIdx.x * 256 + threadIdx.x;          // < 147456
    int c8  = idx & 7;
    int f   = (idx >> 3) & 127;
    int qk  = (idx >> 10) & 3;
    int u   = idx >> 12;                               // 0..35 = cc*9 + tap
    int cc  = u / 9;
    int tap = u - cc * 9;
    wpk[idx] = f2bf(w[(f * C_IN + cc * 32 + qk * 8 + c8) * 9 + tap]);
}

// ---------------- implicit-GEMM conv (pipelined x-pack) ----------------------
// grid 256: (n 32) x (band 8: 4 output rows). Block 256 = 4 waves, 1 block/CU.
// Wave (fh = wave>>1, rp = wave&1): tile 64f x 64pos (2 rows x 32), acc[4][4].
// LDS x tile: 204 positions rr = dh*34 + wp (dh 0..5), 128 ch each;
//   16B chunk qc stored at phys chunk qc ^ (rr & 15).
// x-pack slots: slot = dh*2 + g2 (12 per chunk-group); lane -> (w_ = lane&31,
//   chalf = lane>>5); c0 = ccx*32 + g2*16 + chalf*8; one ds_write_b128/lane.
__global__ __launch_bounds__(256, 1) void conv_gemm_kernel(
    const float* __restrict__ x,
    const unsigned short* __restrict__ wpk,
    const float* __restrict__ bias,
    float* __restrict__ out)
{
    __shared__ alignas(16) unsigned short lds_x[204 * C_IN];    // 52,224 B
    __shared__ alignas(16) unsigned short lds_w[3][3 * 4096];   // 3 x 24,576 B

    const int tid  = threadIdx.x;
    const int lane = tid & 63;
    const int wave = tid >> 6;
    const int qk   = lane >> 4;      // 8-channel k-subgroup 0..3
    const int l15  = lane & 15;
    const int w_    = lane & 31;     // x-pack: column
    const int chalf = lane >> 5;     // x-pack: channel half of 16-group

    const int band = blockIdx.x & 7;
    const int n    = blockIdx.x >> 3;
    const int fh   = wave >> 1;
    const int rp   = wave & 1;
    const int f0   = fh * 64;

    // ================= prologue: borders + chunk-group 0 =====================
    // Border chunks wp=0 / wp=33: zero, all 6 dh rows x 16 chunks (192 writes).
    if (tid < 192) {
        int dh = tid / 32, rem = tid & 31;
        int wp = (rem & 1) * 33, qc = rem >> 1;
        int rr = dh * 34 + wp;
        *(bf16x8*)&lds_x[rr * C_IN + ((qc ^ (rr & 15)) << 3)] =
            (bf16x8){0, 0, 0, 0, 0, 0, 0, 0};
    }
    // cc0 interior: 12 slots split 3/wave.
    #pragma unroll
    for (int sl = 0; sl < 3; ++sl) {
        const int slot = wave * 3 + sl;
        const int dh = slot >> 1, g2 = slot & 1;
        const int h = band * 4 - 1 + dh;
        const bool valid = (h >= 0) && (h < HW);
        const int c0 = g2 * 16 + chalf * 8;
        bf16x8 v;
        if (valid) {
            #pragma unroll
            for (int k = 0; k < 8; ++k)
                v[k] = (short)f2bf(x[((n * C_IN + (c0 + k)) * HW + h) * HW + w_]);
        } else {
            #pragma unroll
            for (int k = 0; k < 8; ++k) v[k] = 0;
        }
        const int rr = dh * 34 + (w_ + 1);
        const int qc = c0 >> 3;
        *(bf16x8*)&lds_x[rr * C_IN + ((qc ^ (rr & 15)) << 3)] = v;
    }
    __builtin_amdgcn_sched_barrier(0);   // x loads consumed before weight issue

    // ---- weight stage: 3 taps (24KB) of chunk cc starting at tap t0 -> lds_w[buf]
    #define STAGE_W3(ccv, t0v, bufv) do {                                       \
        const unsigned short* wsrc = wpk + ((ccv) * 9 + (t0v)) * 4096;          \
        _Pragma("unroll")                                                       \
        for (int j_ = 0; j_ < 6; ++j_) {                                        \
            int p_ = tid + j_ * 256;                                            \
            __builtin_amdgcn_global_load_lds(                                   \
                (const __attribute__((address_space(1))) void*)(wsrc + p_ * 8), \
                (__attribute__((address_space(3))) void*)(&lds_w[bufv][p_ * 8]),\
                16, 0, 0);                                                      \
        }                                                                       \
    } while (0)

    STAGE_W3(0, 0, 0);   // phase 0
    STAGE_W3(0, 3, 1);   // phase 1
    __builtin_amdgcn_sched_barrier(0);

    f32x4 acc[4][4];
    #pragma unroll
    for (int mi = 0; mi < 4; ++mi)
        #pragma unroll
        for (int ni = 0; ni < 4; ++ni)
            acc[mi][ni] = (f32x4){0.f, 0.f, 0.f, 0.f};

    // x position bases per ni: pos p = ni*16 + l15 -> row = p>>5, col = p&31
    int rrb[4];
    #pragma unroll
    for (int ni = 0; ni < 4; ++ni)
        rrb[ni] = (rp * 2 + (ni >> 1)) * HPAD + (ni & 1) * 16 + l15;

    // A-fragment base: f = f0 + mi*16 + l15, channels qk*8..
    const int af_base = qk * 1024 + (f0 + l15) * 8;   // + tl*4096 + mi*128 shorts

    // prologue barrier: x writes visible (lgkm 0), stage0 resident (vmcnt 6)
    asm volatile("s_waitcnt vmcnt(6) lgkmcnt(0)" ::: "memory");
    __builtin_amdgcn_s_barrier();
    __builtin_amdgcn_sched_barrier(0);

    #define COMPUTE3(bufv, ccv, T0)                                             \
        _Pragma("unroll")                                                       \
        for (int tl = 0; tl < 3; ++tl) {                                        \
            const int tap = (T0) + tl;                                          \
            const int r = tap / 3, s = tap - 3 * (tap / 3);                     \
            bf16x8 af[4], bf[4];                                                \
            _Pragma("unroll")                                                   \
            for (int mi = 0; mi < 4; ++mi)                                      \
                af[mi] = *(const bf16x8*)&lds_w[bufv][tl * 4096 + af_base + mi * 128]; \
            _Pragma("unroll")                                                   \
            for (int ni = 0; ni < 4; ++ni) {                                    \
                int rr = rrb[ni] + r * HPAD + s;                                \
                int ph = ((ccv) * 4 + qk) ^ (rr & 15);                          \
                bf[ni] = *(const bf16x8*)&lds_x[rr * C_IN + ph * 8];            \
            }                                                                   \
            _Pragma("unroll")                                                   \
            for (int mi = 0; mi < 4; ++mi)                                      \
                _Pragma("unroll")                                               \
                for (int ni = 0; ni < 4; ++ni)                                  \
                    acc[mi][ni] = __builtin_amdgcn_mfma_f32_16x16x32_bf16(      \
                        af[mi], bf[ni], acc[mi][ni], 0, 0, 0);                  \
        }

    // phase WITHOUT x-pack (p9): stage p+2, compute p, vmcnt(6), barrier.
    #define PHASE_FULL(cc2, t02, b2, bcur, ccv, t0v) do {                       \
        STAGE_W3(cc2, t02, b2);                                                 \
        COMPUTE3(bcur, ccv, t0v);                                               \
        asm volatile("s_waitcnt vmcnt(6)" ::: "memory");                        \
        __builtin_amdgcn_s_barrier();                                           \
        __builtin_amdgcn_sched_barrier(0);                                      \
    } while (0)

    // phase WITH x-pack: issue 8 x loads (chunk-group xcc, slot kk*4+wave) BEFORE
    // the weight stage (pinned), cvt + ds_write AFTER compute. The ds_write's
    // implicit wait drains [x(8), wt p+1(6)] = vmcnt(6); explicit wait is then
    // free. lgkmcnt(0) makes the write visible across waves at the barrier.
    #define PHASE_XW(cc2, t02, b2, bcur, ccv, t0v, xcc, kk) do {                \
        const int slot_ = (kk) * 4 + wave;                                      \
        const int dh_ = slot_ >> 1, g2_ = slot_ & 1;                            \
        const int h_ = band * 4 - 1 + dh_;                                      \
        const bool valid_ = (h_ >= 0) && (h_ < HW);                             \
        const int c0_ = (xcc) * 32 + g2_ * 16 + chalf * 8;                      \
        float xf_[8];                                                           \
        if (valid_) {                                                           \
            _Pragma("unroll")                                                   \
            for (int k2 = 0; k2 < 8; ++k2)                                      \
                xf_[k2] = x[((n * C_IN + (c0_ + k2)) * HW + h_) * HW + w_];     \
        }                                                                       \
        __builtin_amdgcn_sched_barrier(0);                                      \
        STAGE_W3(cc2, t02, b2);                                                 \
        COMPUTE3(bcur, ccv, t0v);                                               \
        __builtin_amdgcn_sched_barrier(0);                                      \
        {                                                                       \
            bf16x8 xv_;                                                         \
            if (valid_) {                                                       \
                _Pragma("unroll")                                               \
                for (int k2 = 0; k2 < 8; ++k2) xv_[k2] = (short)f2bf(xf_[k2]);  \
            } else {                                                            \
                _Pragma("unroll")                                               \
                for (int k2 = 0; k2 < 8; ++k2) xv_[k2] = 0;                     \
            }                                                                   \
            const int rr_ = dh_ * 34 + (w_ + 1);                                \
            const int qc_ = c0_ >> 3;                                           \
            *(bf16x8*)&lds_x[rr_ * C_IN + ((qc_ ^ (rr_ & 15)) << 3)] = xv_;     \
        }                                                                       \
        asm volatile("s_waitcnt vmcnt(6) lgkmcnt(0)" ::: "memory");             \
        __builtin_amdgcn_s_barrier();                                           \
        __builtin_amdgcn_sched_barrier(0);                                      \
    } while (0)

    PHASE_XW(0, 6, 2, 0, 0, 0, 1, 0);   // p0: stage (cc0,t6)->b2, compute cc0 t0, pack cc1 k0
    PHASE_XW(1, 0, 0, 1, 0, 3, 1, 1);   // p1
    PHASE_XW(1, 3, 1, 2, 0, 6, 1, 2);   // p2
    PHASE_XW(1, 6, 2, 0, 1, 0, 2, 0);   // p3
    PHASE_XW(2, 0, 0, 1, 1, 3, 2, 1);   // p4
    PHASE_XW(2, 3, 1, 2, 1, 6, 2, 2);   // p5
    PHASE_XW(2, 6, 2, 0, 2, 0, 3, 0);   // p6
    PHASE_XW(3, 0, 0, 1, 2, 3, 3, 1);   // p7
    PHASE_XW(3, 3, 1, 2, 2, 6, 3, 2);   // p8
    PHASE_FULL(3, 6, 2, 0, 3, 0);       // p9: stage p11, compute cc3 t0
    // p10: nothing left to stage; need p11 done before last phase
    COMPUTE3(1, 3, 3);
    asm volatile("s_waitcnt vmcnt(0)" ::: "memory");
    __builtin_amdgcn_s_barrier();
    __builtin_amdgcn_sched_barrier(0);
    // p11
    COMPUTE3(2, 3, 6);

    // ---- epilogue: D row (f) = qk*4 + reg, col = l15
    const int h0 = band * 4 + rp * 2;
    #pragma unroll
    for (int mi = 0; mi < 4; ++mi) {
        const int f_base = f0 + mi * 16 + qk * 4;
        float bv[4];
        #pragma unroll
        for (int r2 = 0; r2 < 4; ++r2) bv[r2] = bias[f_base + r2];
        #pragma unroll
        for (int ni = 0; ni < 4; ++ni) {
            const int h  = h0 + (ni >> 1);
            const int w2 = (ni & 1) * 16 + l15;
            #pragma unroll
            for (int r2 = 0; r2 < 4; ++r2) {
                out[((unsigned)(n * F_OUT + f_base + r2) * HW + h) * HW + w2] =
                    acc[mi][ni][r2] + bv[r2];
            }
        }
    }
    #undef STAGE_W3
    #undef COMPUTE3
    #undef PHASE_FULL
    #undef PHASE_XW
}

extern "C" void kernel_launch(void* const* d_in, const int* in_sizes, int n_in,
                              void* d_out, int out_size, void* d_ws, size_t ws_size,
                              hipStream_t stream) {
    const float* x = (const float*)d_in[0];
    const float* w = (const float*)d_in[1];
    const float* b = (const float*)d_in[2];
    float* out = (float*)d_out;

    unsigned short* wpk = (unsigned short*)d_ws;   // 4*9*4*128*8 bf16 = 294,912 B

    pack_w_kernel<<<576, 256, 0, stream>>>(w, wpk);
    conv_gemm_kernel<<<N_IMG * 8, 256, 0, stream>>>(x, wpk, b, out);
}

// Round 7
// 84.160 us; speedup vs baseline: 1.0282x; 1.0282x over previous
//
#include <hip/hip_runtime.h>

// Conv2dfft == direct 3x3 cross-correlation, pad=1, + bias (FFT grid never wraps).
// x: [32,128,32,32] f32; w: [128,128,3,3] f32; b: [128] f32; out: [32,128,32,32] f32.
// R9: R7 (best, 83.76us) with the x-pack prologue DE-SERIALIZED: all 96 scalar
// x loads issued back-to-back into registers (xf[12][8], statically indexed,
// ~96 VGPRs -- free at 1 wave/SIMD under launch_bounds(256,1)), then cvt+ds_write
// in a second pass. Removes ~11k cyc of serialized cold-HBM latency per block.
// Main loop / epilogue byte-identical to R7: 12 phases x 3 taps, triple-buffered
// weights staged 2 ahead, counted vmcnt(6), raw s_barrier, XOR-swizzled x tile.

typedef __attribute__((ext_vector_type(8))) short bf16x8;
typedef __attribute__((ext_vector_type(4))) float f32x4;

#define N_IMG 32
#define C_IN  128
#define F_OUT 128
#define HW    32
#define HPAD  34

__device__ __forceinline__ unsigned short f2bf(float f) {
    union { float f; unsigned u; } v; v.f = f;
    unsigned r = v.u + 0x7fffu + ((v.u >> 16) & 1u);   // RNE
    return (unsigned short)(r >> 16);
}

// ------- pack w: [F,C,3,3] f32 -> [cc 4][tap 9][qk 4][f 128][c8 8] bf16 -------
__global__ __launch_bounds__(256) void pack_w_kernel(const float* __restrict__ w,
                                                     unsigned short* __restrict__ wpk) {
    int idx = blockIdx.x * 256 + threadIdx.x;          // < 147456
    int c8  = idx & 7;
    int f   = (idx >> 3) & 127;
    int qk  = (idx >> 10) & 3;
    int u   = idx >> 12;                               // 0..35 = cc*9 + tap
    int cc  = u / 9;
    int tap = u - cc * 9;
    wpk[idx] = f2bf(w[(f * C_IN + cc * 32 + qk * 8 + c8) * 9 + tap]);
}

// ---------------- implicit-GEMM conv (with integrated x-pack) ----------------
// grid 256: (n 32) x (band 8: 4 output rows). Block 256 = 4 waves, 1 block/CU.
// Wave (fh = wave>>1, rp = wave&1): tile 64f x 64pos (2 rows x 32), acc[4][4].
// LDS x tile: 204 positions rr = dh*34 + wp (dh 0..5), 128 ch each;
//   16B chunk qc stored at phys chunk qc ^ (rr & 15).
// Weights: 12 phases (cc, tap-triple), triple-buffer, staged TWO phases ahead,
//   s_waitcnt vmcnt(6) before each barrier (never drains to 0 in the loop).
__global__ __launch_bounds__(256, 1) void conv_gemm_kernel(
    const float* __restrict__ x,
    const unsigned short* __restrict__ wpk,
    const float* __restrict__ bias,
    float* __restrict__ out)
{
    __shared__ alignas(16) unsigned short lds_x[204 * C_IN];    // 52,224 B
    __shared__ alignas(16) unsigned short lds_w[3][3 * 4096];   // 3 x 24,576 B

    const int tid  = threadIdx.x;
    const int lane = tid & 63;
    const int wave = tid >> 6;
    const int qk   = lane >> 4;      // 8-channel k-subgroup 0..3
    const int l15  = lane & 15;

    const int band = blockIdx.x & 7;
    const int n    = blockIdx.x >> 3;
    const int fh   = wave >> 1;
    const int rp   = wave & 1;
    const int f0   = fh * 64;

    // ================= x-pack prologue (replaces pack_x kernel) =============
    // Border chunks wp=0 / wp=33: zero, all 6 dh rows (192 chunks).
    if (tid < 192) {
        int dh = tid / 32, rem = tid & 31;
        int wp = (rem & 1) * 33, qc = rem >> 1;
        int rr = dh * 34 + wp;
        *(bf16x8*)&lds_x[rr * C_IN + ((qc ^ (rr & 15)) << 3)] =
            (bf16x8){0, 0, 0, 0, 0, 0, 0, 0};
    }
    // Interior: 12 slots/wave (dh 0..5 x g2 0..1). Lane: w_ = lane&31 (column),
    // chalf = lane>>5; lane owns channels c0..c0+7 at column w_.
    // PASS 1: issue ALL 96 loads (slots statically unrolled -> all in flight).
    // PASS 2: cvt + one ds_write_b128 per slot.
    {
        const int w_    = lane & 31;
        const int chalf = lane >> 5;
        float xf[12][8];
        #pragma unroll
        for (int slot = 0; slot < 12; ++slot) {
            const int dh = slot >> 1, g2 = slot & 1;
            const int h = band * 4 - 1 + dh;
            const bool valid = (h >= 0) && (h < HW);
            const int c0 = (wave * 2 + g2) * 16 + chalf * 8;
            if (valid) {
                #pragma unroll
                for (int k = 0; k < 8; ++k)
                    xf[slot][k] = x[((n * C_IN + (c0 + k)) * HW + h) * HW + w_];
            } else {
                #pragma unroll
                for (int k = 0; k < 8; ++k) xf[slot][k] = 0.f;
            }
        }
        #pragma unroll
        for (int slot = 0; slot < 12; ++slot) {
            const int dh = slot >> 1, g2 = slot & 1;
            const int c0 = (wave * 2 + g2) * 16 + chalf * 8;
            bf16x8 v;
            #pragma unroll
            for (int k = 0; k < 8; ++k) v[k] = (short)f2bf(xf[slot][k]);
            const int rr = dh * 34 + (w_ + 1);
            const int qc = c0 >> 3;               // logical 16B chunk 0..15
            *(bf16x8*)&lds_x[rr * C_IN + ((qc ^ (rr & 15)) << 3)] = v;
        }
    }
    __builtin_amdgcn_sched_barrier(0);   // all x loads issued+consumed before W issues

    // ---- weight stage: 3 taps (24KB) of chunk cc starting at tap t0 -> lds_w[buf]
    #define STAGE_W3(ccv, t0v, bufv) do {                                       \
        const unsigned short* wsrc = wpk + ((ccv) * 9 + (t0v)) * 4096;          \
        _Pragma("unroll")                                                       \
        for (int j_ = 0; j_ < 6; ++j_) {                                        \
            int p_ = tid + j_ * 256;                                            \
            __builtin_amdgcn_global_load_lds(                                   \
                (const __attribute__((address_space(1))) void*)(wsrc + p_ * 8), \
                (__attribute__((address_space(3))) void*)(&lds_w[bufv][p_ * 8]),\
                16, 0, 0);                                                      \
        }                                                                       \
    } while (0)

    STAGE_W3(0, 0, 0);   // phase 0
    STAGE_W3(0, 3, 1);   // phase 1
    __builtin_amdgcn_sched_barrier(0);

    f32x4 acc[4][4];
    #pragma unroll
    for (int mi = 0; mi < 4; ++mi)
        #pragma unroll
        for (int ni = 0; ni < 4; ++ni)
            acc[mi][ni] = (f32x4){0.f, 0.f, 0.f, 0.f};

    // x position bases per ni: pos p = ni*16 + l15 -> row = p>>5, col = p&31
    int rrb[4];
    #pragma unroll
    for (int ni = 0; ni < 4; ++ni)
        rrb[ni] = (rp * 2 + (ni >> 1)) * HPAD + (ni & 1) * 16 + l15;

    // A-fragment base: f = f0 + mi*16 + l15, channels qk*8..
    const int af_base = qk * 1024 + (f0 + l15) * 8;   // + tl*4096 + mi*128 shorts

    // prologue: x ds_writes visible (lgkm), stage0 resident (vmcnt 6: stage1 in flight)
    asm volatile("s_waitcnt vmcnt(6) lgkmcnt(0)" ::: "memory");
    __builtin_amdgcn_s_barrier();
    __builtin_amdgcn_sched_barrier(0);

    #define COMPUTE3(bufv, ccv, T0)                                             \
        _Pragma("unroll")                                                       \
        for (int tl = 0; tl < 3; ++tl) {                                        \
            const int tap = (T0) + tl;                                          \
            const int r = tap / 3, s = tap - 3 * (tap / 3);                     \
            bf16x8 af[4], bf[4];                                                \
            _Pragma("unroll")                                                   \
            for (int mi = 0; mi < 4; ++mi)                                      \
                af[mi] = *(const bf16x8*)&lds_w[bufv][tl * 4096 + af_base + mi * 128]; \
            _Pragma("unroll")                                                   \
            for (int ni = 0; ni < 4; ++ni) {                                    \
                int rr = rrb[ni] + r * HPAD + s;                                \
                int ph = ((ccv) * 4 + qk) ^ (rr & 15);                          \
                bf[ni] = *(const bf16x8*)&lds_x[rr * C_IN + ph * 8];            \
            }                                                                   \
            _Pragma("unroll")                                                   \
            for (int mi = 0; mi < 4; ++mi)                                      \
                _Pragma("unroll")                                               \
                for (int ni = 0; ni < 4; ++ni)                                  \
                    acc[mi][ni] = __builtin_amdgcn_mfma_f32_16x16x32_bf16(      \
                        af[mi], bf[ni], acc[mi][ni], 0, 0, 0);                  \
        }

    // phase p: stage p+2 (2 ahead), compute p, wait vmcnt(6) (p+1 done, p+2 in
    // flight), barrier.
    #define PHASE_FULL(cc2, t02, b2, bcur, ccv, t0v) do {                       \
        STAGE_W3(cc2, t02, b2);                                                 \
        COMPUTE3(bcur, ccv, t0v);                                               \
        asm volatile("s_waitcnt vmcnt(6)" ::: "memory");                        \
        __builtin_amdgcn_s_barrier();                                           \
        __builtin_amdgcn_sched_barrier(0);                                      \
    } while (0)

    PHASE_FULL(0, 6, 2, 0, 0, 0);   // p0: stage p2 (cc0,t6)->buf2, compute cc0 t0
    PHASE_FULL(1, 0, 0, 1, 0, 3);   // p1: stage p3
    PHASE_FULL(1, 3, 1, 2, 0, 6);   // p2: stage p4
    PHASE_FULL(1, 6, 2, 0, 1, 0);   // p3: stage p5
    PHASE_FULL(2, 0, 0, 1, 1, 3);   // p4: stage p6
    PHASE_FULL(2, 3, 1, 2, 1, 6);   // p5: stage p7
    PHASE_FULL(2, 6, 2, 0, 2, 0);   // p6: stage p8
    PHASE_FULL(3, 0, 0, 1, 2, 3);   // p7: stage p9
    PHASE_FULL(3, 3, 1, 2, 2, 6);   // p8: stage p10
    PHASE_FULL(3, 6, 2, 0, 3, 0);   // p9: stage p11
    // p10: nothing left to stage; need p11 done before last phase
    COMPUTE3(1, 3, 3);
    asm volatile("s_waitcnt vmcnt(0)" ::: "memory");
    __builtin_amdgcn_s_barrier();
    __builtin_amdgcn_sched_barrier(0);
    // p11
    COMPUTE3(2, 3, 6);

    // ---- epilogue: D row (f) = qk*4 + reg, col = l15
    const int h0 = band * 4 + rp * 2;
    #pragma unroll
    for (int mi = 0; mi < 4; ++mi) {
        const int f_base = f0 + mi * 16 + qk * 4;
        float bv[4];
        #pragma unroll
        for (int r2 = 0; r2 < 4; ++r2) bv[r2] = bias[f_base + r2];
        #pragma unroll
        for (int ni = 0; ni < 4; ++ni) {
            const int h  = h0 + (ni >> 1);
            const int w2 = (ni & 1) * 16 + l15;
            #pragma unroll
            for (int r2 = 0; r2 < 4; ++r2) {
                out[((unsigned)(n * F_OUT + f_base + r2) * HW + h) * HW + w2] =
                    acc[mi][ni][r2] + bv[r2];
            }
        }
    }
    #undef STAGE_W3
    #undef COMPUTE3
    #undef PHASE_FULL
}

extern "C" void kernel_launch(void* const* d_in, const int* in_sizes, int n_in,
                              void* d_out, int out_size, void* d_ws, size_t ws_size,
                              hipStream_t stream) {
    const float* x = (const float*)d_in[0];
    const float* w = (const float*)d_in[1];
    const float* b = (const float*)d_in[2];
    float* out = (float*)d_out;

    unsigned short* wpk = (unsigned short*)d_ws;   // 4*9*4*128*8 bf16 = 294,912 B

    pack_w_kernel<<<576, 256, 0, stream>>>(w, wpk);
    conv_gemm_kernel<<<N_IMG * 8, 256, 0, stream>>>(x, wpk, b, out);
}